// Round 4
// baseline (29.484 us; speedup 1.0000x reference)
//
#include <hip/hip_runtime.h>
#include <hip/hip_bf16.h>

// FilterbankLinear: out[b, j*8+o] = sum_{c,t} x[b,c,s_j+t] * w[j*8+o, c*32+t]
// s_j = j (j<4063), s_4063 = 4064.
// Block = 8 windows (508 blocks, grid resident at ~2 blocks/CU), 4 waves.
// Wave handles windows {2wv, 2wv+1} x both 16-batch M-tiles. K = one channel (32).
// x: LDS-staged via coalesced global_load_lds dwordx4, TRIPLE-buffered, depth-2
//    prefetch with COUNTED vmcnt + raw s_barrier (loads stay in flight across
//    barriers -- T4). w: direct float4 register prefetch (T14), no LDS.

#define NF 4096
#define NC 21
#define WIN 32
#define OC 8
#define NWIN 4064
#define NKTOT (OC * NWIN)
#define DD (NC * WIN)       // 672
#define JB 8
#define NBLK (NWIN / JB)    // 508
#define XROWB 272           // 17 chunks * 16B per x row in LDS
#define XBUFB 9216          // 576 chunks * 16B per buffer

typedef short short8 __attribute__((ext_vector_type(8)));
typedef float f32x4 __attribute__((ext_vector_type(4)));

static __device__ __forceinline__ short f2bf(float f) {
  __bf16 h = (__bf16)f;
  return __builtin_bit_cast(short, h);
}
static __device__ __forceinline__ short8 pk8(float a, float b, float c, float d,
                                             float e, float f, float g, float h) {
  short8 v;
  v[0]=f2bf(a); v[1]=f2bf(b); v[2]=f2bf(c); v[3]=f2bf(d);
  v[4]=f2bf(e); v[5]=f2bf(f); v[6]=f2bf(g); v[7]=f2bf(h);
  return v;
}
// select 8 consecutive floats out of 12 by wave-uniform u (static indices only)
static __device__ __forceinline__ short8 sel8(f32x4 a, f32x4 b, f32x4 c, int u) {
  switch (u & 3) {
    case 0:  return pk8(a[0],a[1],a[2],a[3],b[0],b[1],b[2],b[3]);
    case 1:  return pk8(a[1],a[2],a[3],b[0],b[1],b[2],b[3],c[0]);
    case 2:  return pk8(a[2],a[3],b[0],b[1],b[2],b[3],c[0],c[1]);
    default: return pk8(a[3],b[0],b[1],b[2],b[3],c[0],c[1],c[2]);
  }
}

// counted vmcnt wait (never 0 in the main loop), compile-time immediates
static __device__ __forceinline__ void wait_vmcnt(int n) {
  switch (n) {
    case 4: asm volatile("s_waitcnt vmcnt(4)" ::: "memory"); break;
    case 6: asm volatile("s_waitcnt vmcnt(6)" ::: "memory"); break;
    default: asm volatile("s_waitcnt vmcnt(7)" ::: "memory"); break;
  }
}

#define STAGE(GP, I, NB) \
  __builtin_amdgcn_global_load_lds( \
    (const __attribute__((address_space(1))) unsigned int*)(GP), \
    (__attribute__((address_space(3))) unsigned int*)(xlds + (NB)*XBUFB + (I)*1024), \
    16, 0, 0)

__global__ __launch_bounds__(256) void fb_pipe(const float* __restrict__ x,
                                               const float* __restrict__ w,
                                               float* __restrict__ out) {
  __shared__ __align__(16) char xlds[3 * XBUFB];
  const int lane = threadIdx.x & 63;
  const int wv   = threadIdx.x >> 6;

  // bijective XCD swizzle (nwg=508: q=63, r=4)
  const int orig = blockIdx.x;
  const int xcd = orig & 7, idx = orig >> 3;
  const int blk = (xcd < 4 ? xcd * 64 : 256 + (xcd - 4) * 63) + idx;
  const int j0 = blk * JB;
  const int a0 = (j0 < NF - 68) ? j0 : (NF - 68);   // staged span base

  const int n  = lane & 15;
  const int o  = n & 7;
  const int Ck = (lane >> 4) * 2;
  const int boff0 = n * XROWB, boff1 = (16 + n) * XROWB;

  const int jg0 = j0 + 2 * wv, jg1 = jg0 + 1;
  const int s1v = (jg1 == NWIN - 1) ? (NF - WIN) : jg1;
  const int rj0 = jg0 - a0, rj1 = s1v - a0;
  const int u0 = rj0 & 3, u1 = rj1 & 3;
  const int Cw0 = rj0 >> 2, Cw1 = rj1 >> 2;

  // x staging coords: chunks i = 2wv, 2wv+1 per wave; wave 0 also i=8
  const int i0 = 2 * wv, i1 = 2 * wv + 1;
  int q0 = i0 * 64 + lane, q1 = i1 * 64 + lane, q2 = 512 + lane;
  if (q2 > 543) q2 = 543;
  const int b0 = q0 / 17, p0 = q0 - b0 * 17;
  const int b1 = q1 / 17, p1 = q1 - b1 * 17;
  const int b2 = q2 / 17, p2 = q2 - b2 * 17;
  const float* xs0 = x + (size_t)b0 * (NC * NF) + a0 + p0 * 4;
  const float* xs1 = x + (size_t)b1 * (NC * NF) + a0 + p1 * 4;
  const float* xs2 = x + (size_t)b2 * (NC * NF) + a0 + p2 * 4;

  const float* wn0 = w + ((size_t)jg0 * OC + o) * DD + Ck * 4;
  const float* wn1 = w + ((size_t)jg1 * OC + o) * DD + Ck * 4;

  f32x4 acc00 = {0,0,0,0}, acc01 = {0,0,0,0}, acc10 = {0,0,0,0}, acc11 = {0,0,0,0};

  // ---- prologue: stage ch0->B0, ch1->B1; load w(ch0) ----
  STAGE(xs0, i0, 0); STAGE(xs1, i1, 0);
  if (wv == 0) { STAGE(xs2, 8, 0); }
  xs0 += NF; xs1 += NF; xs2 += NF;
  STAGE(xs0, i0, 1); STAGE(xs1, i1, 1);
  if (wv == 0) { STAGE(xs2, 8, 1); }
  xs0 += NF; xs1 += NF; xs2 += NF;
  float4 w0a = *(const float4*)(wn0), w0b = *(const float4*)(wn0 + 4);
  float4 w1a = *(const float4*)(wn1), w1b = *(const float4*)(wn1 + 4);
  wn0 += WIN; wn1 += WIN;

  #pragma unroll
  for (int c = 0; c < NC; ++c) {
    // stage(c) complete; stage(c+1) [2 or 3] + w(c) [4] stay in flight
    if (c < NC - 1) wait_vmcnt(wv == 0 ? 7 : 6);
    else            wait_vmcnt(4);
    __builtin_amdgcn_s_barrier();
    __builtin_amdgcn_sched_barrier(0);

    if (c + 2 < NC) {   // stage channel c+2 into B[(c+2)%3]
      const int nb = (c + 2) % 3;
      STAGE(xs0, i0, nb); STAGE(xs1, i1, nb);
      if (wv == 0) { STAGE(xs2, 8, nb); }
      xs0 += NF; xs1 += NF; xs2 += NF;
    }
    float4 w0an = {0,0,0,0}, w0bn = {0,0,0,0}, w1an = {0,0,0,0}, w1bn = {0,0,0,0};
    if (c + 1 < NC) {   // w prefetch for c+1
      w0an = *(const float4*)(wn0); w0bn = *(const float4*)(wn0 + 4);
      w1an = *(const float4*)(wn1); w1bn = *(const float4*)(wn1 + 4);
      wn0 += WIN; wn1 += WIN;
    }

    const char* xb = xlds + (c % 3) * XBUFB;
    {   // window 0
      short8 fbw = pk8(w0a.x,w0a.y,w0a.z,w0a.w,w0b.x,w0b.y,w0b.z,w0b.w);
      int off = boff0 + (Cw0 + Ck) * 16;
      f32x4 ra = *(const f32x4*)(xb + off);
      f32x4 rb = *(const f32x4*)(xb + off + 16);
      f32x4 rc = *(const f32x4*)(xb + off + 32);
      acc00 = __builtin_amdgcn_mfma_f32_16x16x32_bf16(sel8(ra,rb,rc,u0), fbw, acc00, 0,0,0);
      off = boff1 + (Cw0 + Ck) * 16;
      ra = *(const f32x4*)(xb + off);
      rb = *(const f32x4*)(xb + off + 16);
      rc = *(const f32x4*)(xb + off + 32);
      acc01 = __builtin_amdgcn_mfma_f32_16x16x32_bf16(sel8(ra,rb,rc,u0), fbw, acc01, 0,0,0);
    }
    {   // window 1
      short8 fbw = pk8(w1a.x,w1a.y,w1a.z,w1a.w,w1b.x,w1b.y,w1b.z,w1b.w);
      int off = boff0 + (Cw1 + Ck) * 16;
      f32x4 ra = *(const f32x4*)(xb + off);
      f32x4 rb = *(const f32x4*)(xb + off + 16);
      f32x4 rc = *(const f32x4*)(xb + off + 32);
      acc10 = __builtin_amdgcn_mfma_f32_16x16x32_bf16(sel8(ra,rb,rc,u1), fbw, acc10, 0,0,0);
      off = boff1 + (Cw1 + Ck) * 16;
      ra = *(const f32x4*)(xb + off);
      rb = *(const f32x4*)(xb + off + 16);
      rc = *(const f32x4*)(xb + off + 32);
      acc11 = __builtin_amdgcn_mfma_f32_16x16x32_bf16(sel8(ra,rb,rc,u1), fbw, acc11, 0,0,0);
    }
    w0a = w0an; w0b = w0bn; w1a = w1an; w1b = w1bn;
  }

  if (n < 8) {
    const int m0 = (lane >> 4) * 4;
    #pragma unroll
    for (int e = 0; e < 4; ++e) {
      out[(size_t)(m0 + e)      * NKTOT + (size_t)jg0 * OC + n] = acc00[e];
      out[(size_t)(m0 + e + 16) * NKTOT + (size_t)jg0 * OC + n] = acc01[e];
      out[(size_t)(m0 + e)      * NKTOT + (size_t)jg1 * OC + n] = acc10[e];
      out[(size_t)(m0 + e + 16) * NKTOT + (size_t)jg1 * OC + n] = acc11[e];
    }
  }
}

extern "C" void kernel_launch(void* const* d_in, const int* in_sizes, int n_in,
                              void* d_out, int out_size, void* d_ws, size_t ws_size,
                              hipStream_t stream) {
  const float* x = (const float*)d_in[0];
  const float* w = (const float*)d_in[1];
  float* out = (float*)d_out;
  dim3 grid(NBLK), block(256);
  hipLaunchKernelGGL(fb_pipe, grid, block, 0, stream, x, w, out);
}